// Round 1
// baseline (180.151 us; speedup 1.0000x reference)
//
#include <hip/hip_runtime.h>

#define N_TRACES 128
#define TLEN 32
#define IN_DIM 64
#define HID 128
#define G4 (4 * HID)            // 512 gate rows
#define BATCH (N_TRACES * TLEN) // 4096

// ---------- device helpers ----------

__device__ __forceinline__ float fast_sigmoid(float x) {
    return 1.0f / (1.0f + __expf(-x));
}
// tanh(x) = 1 - 2/(e^{2x}+1): stable at both extremes (no inf/inf)
__device__ __forceinline__ float fast_tanh(float x) {
    return 1.0f - 2.0f / (__expf(2.0f * x) + 1.0f);
}
// sum across the 4 lanes of a quad (lanes 4q..4q+3), result in all 4 lanes
__device__ __forceinline__ float quad_reduce(float x) {
    x += __int_as_float(__builtin_amdgcn_update_dpp(
        0, __float_as_int(x), 0xB1 /*quad_perm [1,0,3,2]*/, 0xF, 0xF, true));
    x += __int_as_float(__builtin_amdgcn_update_dpp(
        0, __float_as_int(x), 0x4E /*quad_perm [2,3,0,1]*/, 0xF, 0xF, true));
    return x;
}

// ---------- generic fp32 GEMM: out[M][N] = A[M][K] * W[N][K]^T + b1[N] + b2[N] ----------
// grid = (M/64, N/64), block = 256 (16x16 threads, 4x4 microtile). K in {64,128}.

template <int K>
__global__ __launch_bounds__(256) void gemm_bt(
    const float* __restrict__ A,
    const float* __restrict__ W,
    const float* __restrict__ b1,
    const float* __restrict__ b2,
    float* __restrict__ out,
    int Nld)
{
    constexpr int LD = 68; // pad 64->68 to break bank alignment
    __shared__ float At[K][LD];
    __shared__ float Wt[K][LD];

    const int tid = threadIdx.x;
    const int m0 = blockIdx.x * 64;
    const int n0 = blockIdx.y * 64;

    // stage tiles transposed: [k][row] so compute reads are contiguous float4
    #pragma unroll
    for (int j = 0; j < K / 16; ++j) {
        const int e = 4 * (tid + 256 * j); // element index in 64xK tile
        const int row = e / K;
        const int k = e % K;
        float4 va = *(const float4*)(A + (size_t)(m0 + row) * K + k);
        At[k + 0][row] = va.x; At[k + 1][row] = va.y;
        At[k + 2][row] = va.z; At[k + 3][row] = va.w;
        float4 vw = *(const float4*)(W + (size_t)(n0 + row) * K + k);
        Wt[k + 0][row] = vw.x; Wt[k + 1][row] = vw.y;
        Wt[k + 2][row] = vw.z; Wt[k + 3][row] = vw.w;
    }
    __syncthreads();

    const int tx = tid & 15;
    const int ty = tid >> 4;
    float acc[4][4] = {};

    #pragma unroll 4
    for (int k = 0; k < K; ++k) {
        float4 a = *(const float4*)&At[k][ty * 4];
        float4 w = *(const float4*)&Wt[k][tx * 4];
        acc[0][0] = fmaf(a.x, w.x, acc[0][0]); acc[0][1] = fmaf(a.x, w.y, acc[0][1]);
        acc[0][2] = fmaf(a.x, w.z, acc[0][2]); acc[0][3] = fmaf(a.x, w.w, acc[0][3]);
        acc[1][0] = fmaf(a.y, w.x, acc[1][0]); acc[1][1] = fmaf(a.y, w.y, acc[1][1]);
        acc[1][2] = fmaf(a.y, w.z, acc[1][2]); acc[1][3] = fmaf(a.y, w.w, acc[1][3]);
        acc[2][0] = fmaf(a.z, w.x, acc[2][0]); acc[2][1] = fmaf(a.z, w.y, acc[2][1]);
        acc[2][2] = fmaf(a.z, w.z, acc[2][2]); acc[2][3] = fmaf(a.z, w.w, acc[2][3]);
        acc[3][0] = fmaf(a.w, w.x, acc[3][0]); acc[3][1] = fmaf(a.w, w.y, acc[3][1]);
        acc[3][2] = fmaf(a.w, w.z, acc[3][2]); acc[3][3] = fmaf(a.w, w.w, acc[3][3]);
    }

    float bb[4];
    #pragma unroll
    for (int j = 0; j < 4; ++j) {
        const int n = n0 + tx * 4 + j;
        bb[j] = b1[n] + b2[n];
    }
    #pragma unroll
    for (int i = 0; i < 4; ++i) {
        const int m = m0 + ty * 4 + i;
        float4 v;
        v.x = acc[i][0] + bb[0]; v.y = acc[i][1] + bb[1];
        v.z = acc[i][2] + bb[2]; v.w = acc[i][3] + bb[3];
        *(float4*)(out + (size_t)m * Nld + n0 + tx * 4) = v;
    }
}

// ---------- LSTM recurrence: one workgroup per trace, W_hh entirely in registers ----------
// thread (u = tid>>2, s = tid&3) holds rows {u, 128+u, 256+u, 384+u}, k in [32s, 32s+32).
// h lives in LDS with word mapping p(k) = k + 4*(k>>5) (stride-36 slices, conflict-free).
// Quad {s=0..3} shares hidden unit u -> DPP quad reduction -> lane s==0 owns c[u],h[u].

__global__ __launch_bounds__(512) void lstm_rec(
    const float* __restrict__ xproj, // [BATCH][512]: precomputed x-projection + both biases
    const float* __restrict__ Whh,   // [512][128]
    float* __restrict__ hout)        // [BATCH][128]
{
    const int trace = blockIdx.x;
    const int tid = threadIdx.x;
    const int u = tid >> 2;
    const int s = tid & 3;

    // load weight block into registers (128 VGPRs)
    float w[4][32];
    #pragma unroll
    for (int i = 0; i < 4; ++i) {
        const float* wr = Whh + (size_t)(u + 128 * i) * HID + 32 * s;
        #pragma unroll
        for (int j = 0; j < 8; ++j) {
            float4 v = *(const float4*)(wr + 4 * j);
            w[i][4 * j + 0] = v.x; w[i][4 * j + 1] = v.y;
            w[i][4 * j + 2] = v.z; w[i][4 * j + 3] = v.w;
        }
    }

    __shared__ float hbuf[2][144]; // double-buffered padded h (p(127)=139 < 144)
    if (tid < 144) { hbuf[0][tid] = 0.0f; hbuf[1][tid] = 0.0f; }

    const float* xpb = xproj + (size_t)trace * TLEN * G4;
    float* hob = hout + (size_t)trace * TLEN * HID;

    float xp[4] = {0.f, 0.f, 0.f, 0.f};
    if (s == 0) {
        #pragma unroll
        for (int i = 0; i < 4; ++i) xp[i] = xpb[u + 128 * i];
    }
    float c = 0.0f;
    __syncthreads();

    #pragma unroll 1
    for (int t = 0; t < TLEN; ++t) {
        // read my k-slice of h(t): words 36*s .. 36*s+31 (16B-aligned)
        const float* hb = &hbuf[t & 1][36 * s];
        float hv[32];
        #pragma unroll
        for (int j = 0; j < 8; ++j) {
            float4 v = *(const float4*)(hb + 4 * j);
            hv[4 * j + 0] = v.x; hv[4 * j + 1] = v.y;
            hv[4 * j + 2] = v.z; hv[4 * j + 3] = v.w;
        }

        // prefetch next step's x-projection while FMAs run
        float xn[4] = {0.f, 0.f, 0.f, 0.f};
        if (s == 0 && t + 1 < TLEN) {
            #pragma unroll
            for (int i = 0; i < 4; ++i) xn[i] = xpb[(t + 1) * G4 + u + 128 * i];
        }

        float acc0 = 0.f, acc1 = 0.f, acc2 = 0.f, acc3 = 0.f;
        #pragma unroll
        for (int j = 0; j < 32; ++j) {
            acc0 = fmaf(w[0][j], hv[j], acc0);
            acc1 = fmaf(w[1][j], hv[j], acc1);
            acc2 = fmaf(w[2][j], hv[j], acc2);
            acc3 = fmaf(w[3][j], hv[j], acc3);
        }
        acc0 = quad_reduce(acc0);
        acc1 = quad_reduce(acc1);
        acc2 = quad_reduce(acc2);
        acc3 = quad_reduce(acc3);

        if (s == 0) {
            const float iv = fast_sigmoid(acc0 + xp[0]);
            const float fv = fast_sigmoid(acc1 + xp[1]);
            const float gv = fast_tanh(acc2 + xp[2]);
            const float ov = fast_sigmoid(acc3 + xp[3]);
            c = fv * c + iv * gv;
            const float h = ov * fast_tanh(c);
            hbuf[(t + 1) & 1][u + 4 * (u >> 5)] = h;
            hob[t * HID + u] = h;
            xp[0] = xn[0]; xp[1] = xn[1]; xp[2] = xn[2]; xp[3] = xn[3];
        }
        __syncthreads();
    }
}

// ---------- final linear: y[r] = dot(A[r][:128], wl) + bl ----------

__global__ __launch_bounds__(256) void rowdot(
    const float* __restrict__ A,  // [BATCH][128]
    const float* __restrict__ wl, // [128]
    const float* __restrict__ bl, // [1]
    float* __restrict__ y)        // [BATCH]
{
    const int r = blockIdx.x * 256 + threadIdx.x;
    const float4* a4 = (const float4*)(A + (size_t)r * HID);
    const float4* w4 = (const float4*)wl;
    float sacc = 0.f;
    #pragma unroll
    for (int j = 0; j < HID / 4; ++j) {
        float4 a = a4[j], w = w4[j];
        sacc = fmaf(a.x, w.x, sacc);
        sacc = fmaf(a.y, w.y, sacc);
        sacc = fmaf(a.z, w.z, sacc);
        sacc = fmaf(a.w, w.w, sacc);
    }
    y[r] = sacc + bl[0];
}

// ---------- launch ----------

extern "C" void kernel_launch(void* const* d_in, const int* in_sizes, int n_in,
                              void* d_out, int out_size, void* d_ws, size_t ws_size,
                              hipStream_t stream) {
    const float* input = (const float*)d_in[0];  // [4096][64]
    const float* W_ih0 = (const float*)d_in[1];  // [512][64]
    const float* W_hh0 = (const float*)d_in[2];  // [512][128]
    const float* b_ih0 = (const float*)d_in[3];  // [512]
    const float* b_hh0 = (const float*)d_in[4];  // [512]
    const float* W_ih1 = (const float*)d_in[5];  // [512][128]
    const float* W_hh1 = (const float*)d_in[6];  // [512][128]
    const float* b_ih1 = (const float*)d_in[7];  // [512]
    const float* b_hh1 = (const float*)d_in[8];  // [512]
    const float* W_lin = (const float*)d_in[9];  // [1][128]
    const float* b_lin = (const float*)d_in[10]; // [1]
    float* out = (float*)d_out;                  // [4096]

    // workspace layout (12 MB): xproj (reused for both layers), h1, h2
    float* xproj = (float*)d_ws;                    // [4096][512]
    float* h1 = xproj + (size_t)BATCH * G4;         // [4096][128]
    float* h2 = h1 + (size_t)BATCH * HID;           // [4096][128]

    dim3 ggrid(BATCH / 64, G4 / 64); // (64, 8)

    // P1: xproj0 = input @ W_ih0^T + b_ih0 + b_hh0
    gemm_bt<IN_DIM><<<ggrid, 256, 0, stream>>>(input, W_ih0, b_ih0, b_hh0, xproj, G4);
    // P2: layer-0 recurrence -> h1
    lstm_rec<<<N_TRACES, 512, 0, stream>>>(xproj, W_hh0, h1);
    // P3: xproj1 = h1 @ W_ih1^T + b_ih1 + b_hh1 (overwrites xproj)
    gemm_bt<HID><<<ggrid, 256, 0, stream>>>(h1, W_ih1, b_ih1, b_hh1, xproj, G4);
    // P4: layer-1 recurrence -> h2
    lstm_rec<<<N_TRACES, 512, 0, stream>>>(xproj, W_hh1, h2);
    // P5: y = h2 @ W_lin^T + b_lin
    rowdot<<<BATCH / 256, 256, 0, stream>>>(h2, W_lin, b_lin, out);
}

// Round 2
// 170.889 us; speedup vs baseline: 1.0542x; 1.0542x over previous
//
#include <hip/hip_runtime.h>

#define N_TRACES 128
#define TLEN 32
#define IN_DIM 64
#define HID 128
#define G4 (4 * HID)            // 512 gate rows
#define BATCH (N_TRACES * TLEN) // 4096

// ---------- device helpers ----------

__device__ __forceinline__ float fast_sigmoid(float x) {
    return 1.0f / (1.0f + __expf(-x));
}
// tanh(x) = 1 - 2/(e^{2x}+1): stable at both extremes
__device__ __forceinline__ float fast_tanh(float x) {
    return 1.0f - 2.0f / (__expf(2.0f * x) + 1.0f);
}
// sum across the 4 lanes of a quad, result in all 4 lanes
__device__ __forceinline__ float quad_reduce(float x) {
    x += __int_as_float(__builtin_amdgcn_update_dpp(
        0, __float_as_int(x), 0xB1 /*quad_perm [1,0,3,2]*/, 0xF, 0xF, true));
    x += __int_as_float(__builtin_amdgcn_update_dpp(
        0, __float_as_int(x), 0x4E /*quad_perm [2,3,0,1]*/, 0xF, 0xF, true));
    return x;
}

// load 4 gate rows {u+128i}, k-slice [32s,32s+32) of a [512][128] matrix into regs
__device__ __forceinline__ void load_w(const float* __restrict__ W, int u, int s,
                                       float (&w)[4][32]) {
    #pragma unroll
    for (int i = 0; i < 4; ++i) {
        const float* wr = W + (size_t)(u + 128 * i) * HID + 32 * s;
        #pragma unroll
        for (int j = 0; j < 8; ++j) {
            float4 v = *(const float4*)(wr + 4 * j);
            w[i][4 * j + 0] = v.x; w[i][4 * j + 1] = v.y;
            w[i][4 * j + 2] = v.z; w[i][4 * j + 3] = v.w;
        }
    }
}

// acc[i] += dot(w[i][:], hb[0:32]) ; hb must be 16B aligned
__device__ __forceinline__ void matvec_acc(const float (&w)[4][32],
                                           const float* hb, float (&acc)[4]) {
    #pragma unroll
    for (int j = 0; j < 8; ++j) {
        float4 v = *(const float4*)(hb + 4 * j);
        float hx[4] = {v.x, v.y, v.z, v.w};
        #pragma unroll
        for (int e = 0; e < 4; ++e) {
            #pragma unroll
            for (int i = 0; i < 4; ++i)
                acc[i] = fmaf(w[i][4 * j + e], hx[e], acc[i]);
        }
    }
}

// ---------- input GEMM: out[M][512] = A[M][64] * W[512][64]^T + b1 + b2 ----------
// grid = (M/64, 8), block = 256 (16x16 threads, 4x4 microtile)

template <int K>
__global__ __launch_bounds__(256) void gemm_bt(
    const float* __restrict__ A,
    const float* __restrict__ W,
    const float* __restrict__ b1,
    const float* __restrict__ b2,
    float* __restrict__ out,
    int Nld)
{
    constexpr int LD = 68;
    __shared__ float At[K][LD];
    __shared__ float Wt[K][LD];

    const int tid = threadIdx.x;
    const int m0 = blockIdx.x * 64;
    const int n0 = blockIdx.y * 64;

    // stage transposed [k][row]; lane-rotated element order breaks the
    // 4*LD-stride write conflict (8/16-way -> ~2-way)
    const int rot = tid & 3;
    #pragma unroll
    for (int j = 0; j < K / 16; ++j) {
        const int e = 4 * (tid + 256 * j);
        const int row = e / K;
        const int k = e % K;
        float4 va = *(const float4*)(A + (size_t)(m0 + row) * K + k);
        float4 vw = *(const float4*)(W + (size_t)(n0 + row) * K + k);
        float fa[4] = {va.x, va.y, va.z, va.w};
        float fw[4] = {vw.x, vw.y, vw.z, vw.w};
        #pragma unroll
        for (int ii = 0; ii < 4; ++ii) {
            const int i = (ii + rot) & 3;
            At[k + i][row] = fa[i];
            Wt[k + i][row] = fw[i];
        }
    }
    __syncthreads();

    const int tx = tid & 15;
    const int ty = tid >> 4;
    float acc[4][4] = {};

    #pragma unroll 4
    for (int k = 0; k < K; ++k) {
        float4 a = *(const float4*)&At[k][ty * 4];
        float4 w = *(const float4*)&Wt[k][tx * 4];
        acc[0][0] = fmaf(a.x, w.x, acc[0][0]); acc[0][1] = fmaf(a.x, w.y, acc[0][1]);
        acc[0][2] = fmaf(a.x, w.z, acc[0][2]); acc[0][3] = fmaf(a.x, w.w, acc[0][3]);
        acc[1][0] = fmaf(a.y, w.x, acc[1][0]); acc[1][1] = fmaf(a.y, w.y, acc[1][1]);
        acc[1][2] = fmaf(a.y, w.z, acc[1][2]); acc[1][3] = fmaf(a.y, w.w, acc[1][3]);
        acc[2][0] = fmaf(a.z, w.x, acc[2][0]); acc[2][1] = fmaf(a.z, w.y, acc[2][1]);
        acc[2][2] = fmaf(a.z, w.z, acc[2][2]); acc[2][3] = fmaf(a.z, w.w, acc[2][3]);
        acc[3][0] = fmaf(a.w, w.x, acc[3][0]); acc[3][1] = fmaf(a.w, w.y, acc[3][1]);
        acc[3][2] = fmaf(a.w, w.z, acc[3][2]); acc[3][3] = fmaf(a.w, w.w, acc[3][3]);
    }

    float bb[4];
    #pragma unroll
    for (int j = 0; j < 4; ++j) {
        const int n = n0 + tx * 4 + j;
        bb[j] = b1[n] + b2[n];
    }
    #pragma unroll
    for (int i = 0; i < 4; ++i) {
        const int m = m0 + ty * 4 + i;
        float4 v;
        v.x = acc[i][0] + bb[0]; v.y = acc[i][1] + bb[1];
        v.z = acc[i][2] + bb[2]; v.w = acc[i][3] + bb[3];
        *(float4*)(out + (size_t)m * Nld + n0 + tx * 4) = v;
    }
}

// ---------- fused per-trace kernel ----------
// One WG (512 threads) per trace. Thread (u=tid>>2, s=tid&3) owns gate rows
// {u+128i} and k-slice [32s,32s+32). Weight matrix of the current phase lives
// in 128 VGPRs. h storage padded: word p(k)=k+4*(k>>5) -> slice s at 36s,
// conflict-free broadcast reads.
// Phases: B = layer0 recurrence (h1 -> LDS), C = xproj1 = W_ih1@h1 + biases
// (no barriers), D = layer1 recurrence (h2 overwrites h1 region), E = readout.

__global__ __launch_bounds__(512, 2) void fused_trace(
    const float* __restrict__ xproj0, // [4096][512] (incl. both layer-0 biases)
    const float* __restrict__ Whh0,   // [512][128]
    const float* __restrict__ Wih1,   // [512][128]
    const float* __restrict__ bih1,   // [512]
    const float* __restrict__ bhh1,   // [512]
    const float* __restrict__ Whh1,   // [512][128]
    const float* __restrict__ Wlin,   // [128]
    const float* __restrict__ blin,   // [1]
    float* __restrict__ y)            // [4096]
{
    const int trace = blockIdx.x;
    const int tid = threadIdx.x;
    const int u = tid >> 2;
    const int s = tid & 3;
    const int pu = u + 4 * (u >> 5); // padded word index for unit u

    __shared__ float hs[TLEN][140];  // h1 then h2, padded (p(127)=139)
    __shared__ float xp1[TLEN][G4];  // layer-1 input projection

    float w[4][32];

    // ===== Phase B: layer-0 recurrence =====
    load_w(Whh0, u, s, w);
    const float* xpb = xproj0 + (size_t)trace * TLEN * G4;
    float xp[4] = {0.f, 0.f, 0.f, 0.f};
    if (s == 0) {
        #pragma unroll
        for (int i = 0; i < 4; ++i) xp[i] = xpb[u + 128 * i];
    }
    float c = 0.0f;
    #pragma unroll 1
    for (int t = 0; t < TLEN; ++t) {
        float acc[4] = {0.f, 0.f, 0.f, 0.f};
        if (t > 0) matvec_acc(w, &hs[t - 1][36 * s], acc);

        float xn[4] = {0.f, 0.f, 0.f, 0.f};
        if (s == 0 && t + 1 < TLEN) {
            #pragma unroll
            for (int i = 0; i < 4; ++i) xn[i] = xpb[(t + 1) * G4 + u + 128 * i];
        }
        #pragma unroll
        for (int i = 0; i < 4; ++i) acc[i] = quad_reduce(acc[i]);

        if (s == 0) {
            const float iv = fast_sigmoid(acc[0] + xp[0]);
            const float fv = fast_sigmoid(acc[1] + xp[1]);
            const float gv = fast_tanh(acc[2] + xp[2]);
            const float ov = fast_sigmoid(acc[3] + xp[3]);
            c = fv * c + iv * gv;
            hs[t][pu] = ov * fast_tanh(c);
            xp[0] = xn[0]; xp[1] = xn[1]; xp[2] = xn[2]; xp[3] = xn[3];
        }
        __syncthreads();
    }

    // ===== Phase C: xp1[t] = W_ih1 @ h1(t) + b_ih1 + b_hh1 (barrier-free) =====
    load_w(Wih1, u, s, w);
    float bi[4] = {0.f, 0.f, 0.f, 0.f};
    if (s == 0) {
        #pragma unroll
        for (int i = 0; i < 4; ++i) bi[i] = bih1[u + 128 * i] + bhh1[u + 128 * i];
    }
    #pragma unroll 1
    for (int t = 0; t < TLEN; ++t) {
        float acc[4] = {0.f, 0.f, 0.f, 0.f};
        matvec_acc(w, &hs[t][36 * s], acc);
        #pragma unroll
        for (int i = 0; i < 4; ++i) acc[i] = quad_reduce(acc[i]);
        if (s == 0) {
            #pragma unroll
            for (int i = 0; i < 4; ++i) xp1[t][u + 128 * i] = acc[i] + bi[i];
        }
    }
    __syncthreads();

    // ===== Phase D: layer-1 recurrence (h2 overwrites hs) =====
    load_w(Whh1, u, s, w);
    c = 0.0f;
    #pragma unroll 1
    for (int t = 0; t < TLEN; ++t) {
        float acc[4] = {0.f, 0.f, 0.f, 0.f};
        if (t > 0) matvec_acc(w, &hs[t - 1][36 * s], acc);
        #pragma unroll
        for (int i = 0; i < 4; ++i) acc[i] = quad_reduce(acc[i]);

        if (s == 0) {
            const float iv = fast_sigmoid(acc[0] + xp1[t][u]);
            const float fv = fast_sigmoid(acc[1] + xp1[t][u + 128]);
            const float gv = fast_tanh(acc[2] + xp1[t][u + 256]);
            const float ov = fast_sigmoid(acc[3] + xp1[t][u + 384]);
            c = fv * c + iv * gv;
            hs[t][pu] = ov * fast_tanh(c);
        }
        __syncthreads();
    }

    // ===== Phase E: y[trace*32+t] = dot(h2(t), W_lin) + b_lin =====
    if (tid < 128) {
        const int tq = tid >> 2;
        const int sq = tid & 3;
        float wl[32];
        #pragma unroll
        for (int j = 0; j < 8; ++j) {
            float4 v = *(const float4*)(Wlin + 32 * sq + 4 * j);
            wl[4 * j + 0] = v.x; wl[4 * j + 1] = v.y;
            wl[4 * j + 2] = v.z; wl[4 * j + 3] = v.w;
        }
        const float* hb = &hs[tq][36 * sq];
        float a = 0.f;
        #pragma unroll
        for (int j = 0; j < 8; ++j) {
            float4 v = *(const float4*)(hb + 4 * j);
            a = fmaf(v.x, wl[4 * j + 0], a);
            a = fmaf(v.y, wl[4 * j + 1], a);
            a = fmaf(v.z, wl[4 * j + 2], a);
            a = fmaf(v.w, wl[4 * j + 3], a);
        }
        a = quad_reduce(a);
        if (sq == 0) y[trace * TLEN + tq] = a + blin[0];
    }
}

// ---------- launch ----------

extern "C" void kernel_launch(void* const* d_in, const int* in_sizes, int n_in,
                              void* d_out, int out_size, void* d_ws, size_t ws_size,
                              hipStream_t stream) {
    const float* input = (const float*)d_in[0];  // [4096][64]
    const float* W_ih0 = (const float*)d_in[1];  // [512][64]
    const float* W_hh0 = (const float*)d_in[2];  // [512][128]
    const float* b_ih0 = (const float*)d_in[3];  // [512]
    const float* b_hh0 = (const float*)d_in[4];  // [512]
    const float* W_ih1 = (const float*)d_in[5];  // [512][128]
    const float* W_hh1 = (const float*)d_in[6];  // [512][128]
    const float* b_ih1 = (const float*)d_in[7];  // [512]
    const float* b_hh1 = (const float*)d_in[8];  // [512]
    const float* W_lin = (const float*)d_in[9];  // [1][128]
    const float* b_lin = (const float*)d_in[10]; // [1]
    float* out = (float*)d_out;                  // [4096]

    float* xproj0 = (float*)d_ws; // [4096][512], 8 MB

    dim3 ggrid(BATCH / 64, G4 / 64); // (64, 8)

    // K1: xproj0 = input @ W_ih0^T + b_ih0 + b_hh0 (full-chip GEMM)
    gemm_bt<IN_DIM><<<ggrid, 256, 0, stream>>>(input, W_ih0, b_ih0, b_hh0, xproj0, G4);
    // K2: fused per-trace LSTM0 -> xproj1 -> LSTM1 -> linear readout
    fused_trace<<<N_TRACES, 512, 0, stream>>>(xproj0, W_hh0, W_ih1, b_ih1, b_hh1,
                                              W_hh1, W_lin, b_lin, out);
}